// Round 8
// baseline (307.750 us; speedup 1.0000x reference)
//
#include <hip/hip_runtime.h>

typedef _Float16 half8 __attribute__((ext_vector_type(8)));
typedef float floatx4 __attribute__((ext_vector_type(4)));

#define DEVI __device__ __forceinline__
#define AS1 __attribute__((address_space(1)))
#define AS3 __attribute__((address_space(3)))
#define GLL(gp, lp) __builtin_amdgcn_global_load_lds((const AS1 void*)(gp), (AS3 void*)(lp), 16, 0, 0)
#define VM0 asm volatile("s_waitcnt vmcnt(0)" ::: "memory")
#define BAR __builtin_amdgcn_s_barrier()

namespace {
constexpr int C_   = 256;
constexpr int DHW_ = 8192;
constexpr int N_   = 16384;   // rows = B*D*H*W
constexpr int NE_  = 8192;    // codebook entries
constexpr int K_   = 256;     // embedding dim

constexpr size_t LOSS_OFF  = 4194304;
constexpr size_t PERP_OFF  = 4194305;
constexpr size_t ENC_OFF   = 4194306;
constexpr size_t ENC_N     = 134217728ull;
constexpr size_t IDX_OFF   = ENC_OFF + ENC_N;

// scratch offsets from 256B-aligned base inside enc-region tail
// (everything here is consumed before vq_zero_tail wipes it)
constexpr size_t SCR_ZH   = 480ull << 20;  // blocked 16384x256 f16 = 8 MiB
constexpr size_t SCR_ZL   = 488ull << 20;
constexpr size_t SCR_EH   = 496ull << 20;  // blocked 8192x256 f16 = 4 MiB
constexpr size_t SCR_EL   = 500ull << 20;
constexpr size_t SCR_ZZ   = 504ull << 20;  // 16384 f32
constexpr size_t SCR_KEY  = 505ull << 20;  // 16384 u64
constexpr size_t SCR_PART = 506ull << 20;  // loss partials f32
constexpr size_t SCR_HIST = 507ull << 20;  // 8192 i32

constexpr int NLOSS_BLOCKS = 2048;

// enc zero-fill split: gemm blocks NT-store [8, 8+8192*61440); tail kernel does the rest.
constexpr size_t ZFILL_PER_BLK = 61440;                       // 15 x 4KB rounds
constexpr size_t TAIL_START    = 8 + 8192ull * ZFILL_PER_BLK; // 503316488
constexpr size_t TAIL_F4       = (536870904ull - TAIL_START) / 16;  // 2097151
}

// Blocked layouts (staging contiguous 16B/lane; LDS conflict-free):
//   A (Z): bytes = tile256*131072 + chunk*16384 + oct*4096 + row*16   (row in tile)
//   B (E): bytes = tile128*65536  + chunk*8192  + oct*2048 + row*16

// ---------------- fused split: z and codebook -> blocked f16 splits ----------------
__global__ void vq_split(const float* __restrict__ z, const float* __restrict__ cb,
                         _Float16* __restrict__ ZHb, _Float16* __restrict__ ZLb,
                         _Float16* __restrict__ EHb, _Float16* __restrict__ ELb,
                         float* __restrict__ zz, unsigned long long* __restrict__ keys,
                         int* __restrict__ hist) {
    __shared__ float tile[64][260];
    int t = threadIdx.x;
    if (blockIdx.x < 512) {
        // ---- Z path: rows n0..n0+31 ----
        int n0 = blockIdx.x * 32;
        int b  = n0 >> 13;
        int d0 = n0 & 8191;
        const float* zb = z + (size_t)b * (C_ * DHW_) + d0;
        int j5 = t & 31, cg8 = t >> 5;          // 8 c-groups
        for (int cc = 0; cc < 256; cc += 8) {
            int c = cc + cg8;
            tile[j5][c] = zb[(size_t)c * DHW_ + j5];   // coalesced over j5
        }
        __syncthreads();
        int tl = n0 >> 8, r0 = n0 & 255;
        #pragma unroll
        for (int it = 0; it < 4; ++it) {
            int rid = it * 8 + cg8;                    // k-octet 0..31
            half8 h, l;
            #pragma unroll
            for (int e = 0; e < 8; ++e) {
                float v = tile[j5][rid * 8 + e];
                _Float16 hh = (_Float16)v;
                h[e] = hh;
                l[e] = (_Float16)((v - (float)hh) * 2048.0f);  // residual scaled 2^11
            }
            size_t off = ((size_t)(tl * 8 + (rid >> 2))) * 8192
                       + (size_t)(rid & 3) * 2048 + (size_t)(r0 + j5) * 8;
            *(half8*)(ZHb + off) = h;
            *(half8*)(ZLb + off) = l;
        }
        // zz (same per-row math as the passing rounds; only binade matters)
        if (t < 32) {
            float tot[2];
            for (int h2 = 0; h2 < 2; ++h2) {
                float r8[8];
                #pragma unroll
                for (int k = 0; k < 8; ++k) { float x = tile[t][h2*128 + k]; r8[k] = x * x; }
                for (int i = 8; i < 128; i += 8) {
                    #pragma unroll
                    for (int k = 0; k < 8; ++k) { float x = tile[t][h2*128 + i + k]; r8[k] += x * x; }
                }
                tot[h2] = ((r8[0]+r8[1]) + (r8[2]+r8[3])) + ((r8[4]+r8[5]) + (r8[6]+r8[7]));
            }
            zz[n0 + t] = tot[0] + tot[1];
        }
        if (blockIdx.x < 64) keys[blockIdx.x * 256 + t] = ~0ull;
        else if (blockIdx.x < 96) hist[(blockIdx.x - 64) * 256 + t] = 0;
    } else {
        // ---- E path: codebook rows j0..j0+63, pre-scaled by 2^16 (exact) ----
        int j = t & 63, grp = t >> 6;
        int j0 = (blockIdx.x - 512) * 64;
        for (int i = 0; i < 64; ++i)
            tile[i][t] = cb[(size_t)(j0 + i) * K_ + t] * 65536.0f;   // coalesced over t
        __syncthreads();
        int tl = j0 >> 7, r0 = j0 & 127;
        #pragma unroll
        for (int it = 0; it < 8; ++it) {
            int rid = it * 4 + grp;
            half8 h, l;
            #pragma unroll
            for (int e = 0; e < 8; ++e) {
                float v = tile[j][rid * 8 + e];
                _Float16 hh = (_Float16)v;
                h[e] = hh;
                l[e] = (_Float16)((v - (float)hh) * 2048.0f);
            }
            size_t off = ((size_t)(tl * 8 + (rid >> 2))) * 4096
                       + (size_t)(rid & 3) * 1024 + (size_t)(r0 + j) * 8;
            *(half8*)(EHb + off) = h;
            *(half8*)(ELb + off) = l;
        }
    }
}

// ---------------- GEMM + fused argmin + enc zero-fill absorption ----------------
// TM=TN=128, KC=32, 8 chunks, 4 waves (2x2), 2 blocks/CU.
// A (ZH/ZL) fragments are loaded DIRECTLY from global (L2-hot, XCD-local by
// swizzle): halves LDS read traffic and halves GLL staging writes.
// Only B (EH/EL) is LDS-staged: 2 buffers x 16KB.
// Per iter: [8 A-loads][8 B ds_reads][4 GLL stage(c+1)][2 NT zfill][48 MFMA].
// Compiler's wait-for-A (oldest VMEM) does not drain the newer GLLs ->
// stage(c+1) stays in flight under the MFMA cluster. VM0+BAR hands off LDS.

DEVI void stage_chunkB(const char* eh, const char* el, char* b, int t, int c) {
    #pragma unroll
    for (int i = 0; i < 2; ++i) {
        int f = i * 256 + t;                       // 0..511 = oct*128 + col
        int eo = (f >> 7) * 2048 + (f & 127) * 16; // src offset within chunk
        GLL(eh + (size_t)c * 8192 + eo, b + f * 16);
        GLL(el + (size_t)c * 8192 + eo, b + 8192 + f * 16);
    }
}

DEVI void gemm_iter(const char* zh, const char* zl, int c,
                    const char* Lc, const char* eh, const char* el, char* Ln, bool last,
                    char* zb, int r0, int nfill,
                    int wm, int wn, int g, int rr, int t,
                    floatx4 (&acc_a)[4][4], floatx4 (&acc_b)[4][4]) {
    const char* Bb = Lc + g * 2048;
    half8 azh[4], azl[4], beh[4], bel[4];
    size_t abase = (size_t)c * 16384 + (size_t)g * 4096;
    #pragma unroll
    for (int f = 0; f < 4; ++f) {
        int row = wm * 64 + f * 16 + rr;
        azh[f] = *(const half8*)(zh + abase + row * 16);   // global, L2-hot
        azl[f] = *(const half8*)(zl + abase + row * 16);
    }
    #pragma unroll
    for (int f = 0; f < 4; ++f) {
        int col = wn * 64 + f * 16 + rr;
        beh[f] = *(const half8*)(Bb + col * 16);           // LDS
        bel[f] = *(const half8*)(Bb + 8192 + col * 16);
    }
    if (!last) stage_chunkB(eh, el, Ln, t, c + 1);
    floatx4 z4 = {0.f, 0.f, 0.f, 0.f};
    if (nfill >= 1) __builtin_nontemporal_store(z4, (floatx4*)(zb + (size_t)r0 * 4096 + t * 16));
    if (nfill >= 2) __builtin_nontemporal_store(z4, (floatx4*)(zb + (size_t)(r0 + 1) * 4096 + t * 16));
    __builtin_amdgcn_s_setprio(1);
    #pragma unroll
    for (int fi = 0; fi < 4; ++fi)
        #pragma unroll
        for (int fj = 0; fj < 4; ++fj) {
            acc_a[fi][fj] = __builtin_amdgcn_mfma_f32_16x16x32_f16(azh[fi], beh[fj], acc_a[fi][fj], 0, 0, 0);
            acc_b[fi][fj] = __builtin_amdgcn_mfma_f32_16x16x32_f16(azl[fi], beh[fj], acc_b[fi][fj], 0, 0, 0);
            acc_b[fi][fj] = __builtin_amdgcn_mfma_f32_16x16x32_f16(azh[fi], bel[fj], acc_b[fi][fj], 0, 0, 0);
        }
    __builtin_amdgcn_s_setprio(0);
}

__launch_bounds__(256, 2)
__global__ void vq_gemm_argmin(const _Float16* __restrict__ ZHb, const _Float16* __restrict__ ZLb,
                               const _Float16* __restrict__ EHb, const _Float16* __restrict__ ELb,
                               const float* __restrict__ zz,
                               unsigned long long* __restrict__ keys,
                               char* __restrict__ zfill) {
    __shared__ _Float16 lds[2][8192];                 // 2 x 16KB (B only)
    __shared__ unsigned long long rowmin[128];

    // XCD-locality: xcd owns bm in [16x, 16x+16), sweeps bn
    int orig = blockIdx.x;
    int xcd = orig & 7;
    int loc = orig >> 3;                 // 0..1023
    int bm = xcd * 16 + (loc & 15);      // 0..127 (128-row Z slices)
    int bn = loc >> 4;                   // 0..63  (128-row E tiles)
    int m0 = bm * 128, n0v = bn * 128;

    int t = threadIdx.x;
    int lane = t & 63, wid = t >> 6;
    int wm = wid >> 1, wn = wid & 1;     // 2x2 waves of 64x64
    int g = lane >> 4, rr = lane & 15;

    // A slice = half of a 256-row blocked tile
    const char* zh = (const char*)ZHb + (size_t)(bm >> 1) * 131072 + (size_t)(bm & 1) * 2048;
    const char* zl = (const char*)ZLb + (size_t)(bm >> 1) * 131072 + (size_t)(bm & 1) * 2048;
    const char* eh = (const char*)EHb + (size_t)bn * 65536;
    const char* el = (const char*)ELb + (size_t)bn * 65536;
    char* zb = zfill + (size_t)orig * ZFILL_PER_BLK;   // this block's 60KB of enc zeros

    floatx4 acc_a[4][4], acc_b[4][4];
    #pragma unroll
    for (int i = 0; i < 4; ++i)
        #pragma unroll
        for (int jj = 0; jj < 4; ++jj) {
            acc_a[i][jj] = (floatx4){0.f, 0.f, 0.f, 0.f};
            acc_b[i][jj] = (floatx4){0.f, 0.f, 0.f, 0.f};
        }

    char* L0 = (char*)lds[0];
    char* L1 = (char*)lds[1];

    stage_chunkB(eh, el, L0, t, 0);
    VM0; BAR;
    gemm_iter(zh, zl, 0, L0, eh, el, L1, false, zb, 0,  2, wm, wn, g, rr, t, acc_a, acc_b); VM0; BAR;
    gemm_iter(zh, zl, 1, L1, eh, el, L0, false, zb, 2,  2, wm, wn, g, rr, t, acc_a, acc_b); VM0; BAR;
    gemm_iter(zh, zl, 2, L0, eh, el, L1, false, zb, 4,  2, wm, wn, g, rr, t, acc_a, acc_b); VM0; BAR;
    gemm_iter(zh, zl, 3, L1, eh, el, L0, false, zb, 6,  2, wm, wn, g, rr, t, acc_a, acc_b); VM0; BAR;
    gemm_iter(zh, zl, 4, L0, eh, el, L1, false, zb, 8,  2, wm, wn, g, rr, t, acc_a, acc_b); VM0; BAR;
    gemm_iter(zh, zl, 5, L1, eh, el, L0, false, zb, 10, 2, wm, wn, g, rr, t, acc_a, acc_b); VM0; BAR;
    gemm_iter(zh, zl, 6, L0, eh, el, L1, false, zb, 12, 2, wm, wn, g, rr, t, acc_a, acc_b); VM0; BAR;
    gemm_iter(zh, zl, 7, L1, eh, el, L0, true,  zb, 14, 1, wm, wn, g, rr, t, acc_a, acc_b);

    if (t < 128) rowmin[t] = ~0ull;
    __syncthreads();

    constexpr float S_A = 1.0f / 65536.0f;       // 2^-16
    constexpr float S_B = 1.0f / 134217728.0f;   // 2^-27
    #pragma unroll
    for (int fi = 0; fi < 4; ++fi) {
        #pragma unroll
        for (int r = 0; r < 4; ++r) {
            int rowl = wm * 64 + fi * 16 + g * 4 + r;
            float zzv = zz[m0 + rowl];
            unsigned long long best = ~0ull;
            #pragma unroll
            for (int fj = 0; fj < 4; ++fj) {
                float dot = acc_a[fi][fj][r] * S_A + acc_b[fi][fj][r] * S_B;
                float d = zzv - 2.0f * dot;              // replicates ref fl(zz - fl(2*dot))
                unsigned int db = __float_as_uint(d);    // d > 0 -> bit order == float order
                unsigned int jg = (unsigned)(n0v + wn * 64 + fj * 16 + rr);
                unsigned long long key = ((unsigned long long)db << 32) | jg;
                if (key < best) best = key;
            }
            // cross-lane min over the 16 rr-lanes (same rowl) -> conflict-free atomic
            #pragma unroll
            for (int s = 1; s < 16; s <<= 1) {
                unsigned long long o = __shfl_xor(best, s, 64);
                if (o < best) best = o;
            }
            if (rr == 0) atomicMin(&rowmin[rowl], best);
        }
    }
    __syncthreads();
    if (t < 128) atomicMin(&keys[m0 + t], rowmin[t]);
}

// ---------------- z_q + loss partials + idx output + histogram (fused) ----------------
__global__ void vq_zq_loss(const float* __restrict__ z, const float* __restrict__ cb,
                           const unsigned long long* __restrict__ keys,
                           float* __restrict__ out0, float* __restrict__ parts,
                           float* __restrict__ out_idx, int* __restrict__ hist) {
    size_t i0 = ((size_t)blockIdx.x * 256 + threadIdx.x) * 8;
    int c   = (int)((i0 >> 13) & 255);
    int b   = (int)(i0 >> 21);
    int dhw = (int)(i0 & 8191);
    int nb  = b * DHW_ + dhw;
    int jj[8];
    #pragma unroll
    for (int e = 0; e < 8; ++e)
        jj[e] = (int)(unsigned)(keys[nb + e] & 0xFFFFFFFFull);
    float ls = 0.f;
    #pragma unroll
    for (int e = 0; e < 8; ++e) {
        float zq = cb[(size_t)jj[e] * K_ + c];
        float zt = z[i0 + e];
        float diff = zq - zt;        // fl, matches ref
        out0[i0 + e] = zt + diff;    // fl(z_t + fl(z_q - z_t))
        ls += diff * diff;
    }
    if (c == 0) {
        #pragma unroll
        for (int e = 0; e < 8; ++e) {
            out_idx[nb + e] = (float)jj[e];
            atomicAdd(&hist[jj[e]], 1);
        }
    }
    __shared__ float red[256];
    red[threadIdx.x] = ls;
    __syncthreads();
    for (int s = 128; s > 0; s >>= 1) {
        if (threadIdx.x < (unsigned)s) red[threadIdx.x] += red[threadIdx.x + s];
        __syncthreads();
    }
    if (threadIdx.x == 0) parts[blockIdx.x] = red[0];
}

// ---------------- loss + perplexity ----------------
__global__ void vq_finalize_scalars(const float* __restrict__ parts,
                                    const int* __restrict__ hist,
                                    float* __restrict__ out) {
    __shared__ double dred[256];
    int t = threadIdx.x;
    double ent = 0.0;
    for (int i = t; i < NE_; i += 256) {
        float em = (float)hist[i] * (1.0f / 16384.0f);   // exact (pow2)
        float term = em * logf(em + 1e-10f);
        ent += (double)term;
    }
    dred[t] = ent;
    __syncthreads();
    for (int s = 128; s > 0; s >>= 1) {
        if (t < s) dred[t] += dred[t + s];
        __syncthreads();
    }
    double entr = 0.0;
    if (t == 0) entr = dred[0];
    __syncthreads();
    double ls = 0.0;
    for (int i = t; i < NLOSS_BLOCKS; i += 256) ls += (double)parts[i];
    dred[t] = ls;
    __syncthreads();
    for (int s = 128; s > 0; s >>= 1) {
        if (t < s) dred[t] += dred[t + s];
        __syncthreads();
    }
    if (t == 0) {
        double m = dred[0] / 4194304.0;
        float m1 = (float)m;
        out[LOSS_OFF] = m1 + 0.25f * m1;
        out[PERP_OFF] = (float)exp(-entr);
    }
}

// ---------------- zero the scratch tail + head/tail slivers of enc ----------------
__global__ void vq_zero_tail(char* __restrict__ encb) {
    size_t i = (size_t)blockIdx.x * 256 + threadIdx.x;
    floatx4 z4 = {0.f, 0.f, 0.f, 0.f};
    char* base = encb + TAIL_START;
    for (size_t k = i; k < TAIL_F4; k += 131072)
        *(floatx4*)(base + k * 16) = z4;
    if (i == 0) {
        float2 z2 = {0.f, 0.f};
        *(float2*)encb = z2;                      // enc[0..1]
        *(float2*)(encb + 536870904ull) = z2;     // enc[last two]
    }
}

// ---------------- place the ones ----------------
__global__ void vq_write_ones(const float* __restrict__ idxf, float* __restrict__ enc) {
    int n = blockIdx.x * 256 + threadIdx.x;
    enc[(size_t)n * NE_ + (int)idxf[n]] = 1.0f;
}

extern "C" void kernel_launch(void* const* d_in, const int* in_sizes, int n_in,
                              void* d_out, int out_size, void* d_ws, size_t ws_size,
                              hipStream_t stream) {
    const float* z  = (const float*)d_in[0];
    const float* cb = (const float*)d_in[1];
    float* out = (float*)d_out;

    // 256B-aligned scratch base inside the enc-region tail
    char* scr = (char*)(((uintptr_t)(out + ENC_OFF) + 255) & ~(uintptr_t)255);
    _Float16* ZHb = (_Float16*)(scr + SCR_ZH);
    _Float16* ZLb = (_Float16*)(scr + SCR_ZL);
    _Float16* EHb = (_Float16*)(scr + SCR_EH);
    _Float16* ELb = (_Float16*)(scr + SCR_EL);
    float* zz = (float*)(scr + SCR_ZZ);
    unsigned long long* keys = (unsigned long long*)(scr + SCR_KEY);
    float* parts = (float*)(scr + SCR_PART);
    int* hist = (int*)(scr + SCR_HIST);
    float* out_idx = out + IDX_OFF;
    float* enc = out + ENC_OFF;
    char* encb = (char*)enc;

    vq_split<<<640, 256, 0, stream>>>(z, cb, ZHb, ZLb, EHb, ELb, zz, keys, hist);
    vq_gemm_argmin<<<8192, 256, 0, stream>>>(ZHb, ZLb, EHb, ELb, zz, keys, encb + 8);
    vq_zq_loss<<<NLOSS_BLOCKS, 256, 0, stream>>>(z, cb, keys, out, parts, out_idx, hist);
    vq_finalize_scalars<<<1, 256, 0, stream>>>(parts, hist, out);
    vq_zero_tail<<<512, 256, 0, stream>>>(encb);
    vq_write_ones<<<64, 256, 0, stream>>>(out_idx, enc);
}

// Round 9
// 291.882 us; speedup vs baseline: 1.0544x; 1.0544x over previous
//
#include <hip/hip_runtime.h>

typedef _Float16 half8 __attribute__((ext_vector_type(8)));
typedef float floatx4 __attribute__((ext_vector_type(4)));

#define DEVI __device__ __forceinline__
#define AS1 __attribute__((address_space(1)))
#define AS3 __attribute__((address_space(3)))
#define GLL(gp, lp) __builtin_amdgcn_global_load_lds((const AS1 void*)(gp), (AS3 void*)(lp), 16, 0, 0)
#define VM6 asm volatile("s_waitcnt vmcnt(6)" ::: "memory")
#define VM8 asm volatile("s_waitcnt vmcnt(8)" ::: "memory")
#define VM2 asm volatile("s_waitcnt vmcnt(2)" ::: "memory")
#define BAR __builtin_amdgcn_s_barrier()

namespace {
constexpr int C_   = 256;
constexpr int DHW_ = 8192;
constexpr int N_   = 16384;   // rows = B*D*H*W
constexpr int NE_  = 8192;    // codebook entries
constexpr int K_   = 256;     // embedding dim

constexpr size_t LOSS_OFF  = 4194304;
constexpr size_t PERP_OFF  = 4194305;
constexpr size_t ENC_OFF   = 4194306;
constexpr size_t ENC_N     = 134217728ull;
constexpr size_t IDX_OFF   = ENC_OFF + ENC_N;

// scratch offsets from 256B-aligned base inside enc-region tail
// (everything here is consumed before vq_zero_tail wipes it)
constexpr size_t SCR_ZH   = 480ull << 20;  // blocked 16384x256 f16 = 8 MiB
constexpr size_t SCR_ZL   = 488ull << 20;
constexpr size_t SCR_EH   = 496ull << 20;  // blocked 8192x256 f16 = 4 MiB
constexpr size_t SCR_EL   = 500ull << 20;
constexpr size_t SCR_ZZ   = 504ull << 20;  // 16384 f32
constexpr size_t SCR_KEY  = 505ull << 20;  // 16384 u64
constexpr size_t SCR_PART = 506ull << 20;  // loss partials f32
constexpr size_t SCR_HIST = 507ull << 20;  // 8192 i32

constexpr int NLOSS_BLOCKS = 2048;

// enc zero-fill: 4096 gemm blocks NT-store 120KB each starting at encb+8.
constexpr size_t ZFILL_PER_BLK = 122880;                       // 15 x 8KB rounds
constexpr size_t TAIL_START    = 8 + 4096ull * ZFILL_PER_BLK;  // 503316488
constexpr size_t TAIL_F4       = (536870904ull - TAIL_START) / 16;  // 2097151
}

// Blocked layouts (staging contiguous 16B/lane; LDS conflict-free):
//   A (Z): bytes = tile256*131072 + chunk*16384 + oct*4096 + row*16   (row in tile)
//   B (E): bytes = tile128*65536  + chunk*8192  + oct*2048 + row*16

// ---------------- fused split: z and codebook -> blocked f16 splits ----------------
__global__ void vq_split(const float* __restrict__ z, const float* __restrict__ cb,
                         _Float16* __restrict__ ZHb, _Float16* __restrict__ ZLb,
                         _Float16* __restrict__ EHb, _Float16* __restrict__ ELb,
                         float* __restrict__ zz, unsigned long long* __restrict__ keys,
                         int* __restrict__ hist) {
    __shared__ float tile[64][260];
    int t = threadIdx.x;
    if (blockIdx.x < 512) {
        // ---- Z path: rows n0..n0+31 ----
        int n0 = blockIdx.x * 32;
        int b  = n0 >> 13;
        int d0 = n0 & 8191;
        const float* zb = z + (size_t)b * (C_ * DHW_) + d0;
        int j5 = t & 31, cg8 = t >> 5;          // 8 c-groups
        for (int cc = 0; cc < 256; cc += 8) {
            int c = cc + cg8;
            tile[j5][c] = zb[(size_t)c * DHW_ + j5];   // coalesced over j5
        }
        __syncthreads();
        int tl = n0 >> 8, r0 = n0 & 255;
        #pragma unroll
        for (int it = 0; it < 4; ++it) {
            int rid = it * 8 + cg8;                    // k-octet 0..31
            half8 h, l;
            #pragma unroll
            for (int e = 0; e < 8; ++e) {
                float v = tile[j5][rid * 8 + e];
                _Float16 hh = (_Float16)v;
                h[e] = hh;
                l[e] = (_Float16)((v - (float)hh) * 2048.0f);  // residual scaled 2^11
            }
            size_t off = ((size_t)(tl * 8 + (rid >> 2))) * 8192
                       + (size_t)(rid & 3) * 2048 + (size_t)(r0 + j5) * 8;
            *(half8*)(ZHb + off) = h;
            *(half8*)(ZLb + off) = l;
        }
        // zz (same per-row math as the passing rounds; only binade matters)
        if (t < 32) {
            float tot[2];
            for (int h2 = 0; h2 < 2; ++h2) {
                float r8[8];
                #pragma unroll
                for (int k = 0; k < 8; ++k) { float x = tile[t][h2*128 + k]; r8[k] = x * x; }
                for (int i = 8; i < 128; i += 8) {
                    #pragma unroll
                    for (int k = 0; k < 8; ++k) { float x = tile[t][h2*128 + i + k]; r8[k] += x * x; }
                }
                tot[h2] = ((r8[0]+r8[1]) + (r8[2]+r8[3])) + ((r8[4]+r8[5]) + (r8[6]+r8[7]));
            }
            zz[n0 + t] = tot[0] + tot[1];
        }
        if (blockIdx.x < 64) keys[blockIdx.x * 256 + t] = ~0ull;
        else if (blockIdx.x < 96) hist[(blockIdx.x - 64) * 256 + t] = 0;
    } else {
        // ---- E path: codebook rows j0..j0+63, pre-scaled by 2^16 (exact) ----
        int j = t & 63, grp = t >> 6;
        int j0 = (blockIdx.x - 512) * 64;
        for (int i = 0; i < 64; ++i)
            tile[i][t] = cb[(size_t)(j0 + i) * K_ + t] * 65536.0f;   // coalesced over t
        __syncthreads();
        int tl = j0 >> 7, r0 = j0 & 127;
        #pragma unroll
        for (int it = 0; it < 8; ++it) {
            int rid = it * 4 + grp;
            half8 h, l;
            #pragma unroll
            for (int e = 0; e < 8; ++e) {
                float v = tile[j][rid * 8 + e];
                _Float16 hh = (_Float16)v;
                h[e] = hh;
                l[e] = (_Float16)((v - (float)hh) * 2048.0f);
            }
            size_t off = ((size_t)(tl * 8 + (rid >> 2))) * 4096
                       + (size_t)(rid & 3) * 1024 + (size_t)(r0 + j) * 8;
            *(half8*)(EHb + off) = h;
            *(half8*)(ELb + off) = l;
        }
    }
}

// ---------------- GEMM + fused argmin + enc zero-fill absorption ----------------
// BM=256, BN=128, KC=32, 8 chunks, 8 waves (4x2, 512 thr), 1 block/CU.
// 3 LDS buffers x 48KB: ZH[4oct][256][16B] | ZL | EH[4oct][128][16B] | EL.
// Counted-vmcnt pipeline: iter k stages c(k+2) -> every stage has TWO compute
// phases of latency cover; uniform vmcnt(8) leaves {c(k+2):6, NT:2} in flight.
// No barrier ever drains in-flight staging (the m97-ceiling stall).

DEVI void stage_chunk(const char* zh, const char* zl, const char* eh, const char* el,
                      char* b, int t, int c) {
    #pragma unroll
    for (int i = 0; i < 2; ++i) {
        int f = i * 512 + t;                        // 0..1023 = oct*256 + row
        int ao = (f >> 8) * 4096 + (f & 255) * 16;
        GLL(zh + (size_t)c * 16384 + ao, b + f * 16);
    }
    #pragma unroll
    for (int i = 0; i < 2; ++i) {
        int f = i * 512 + t;
        int ao = (f >> 8) * 4096 + (f & 255) * 16;
        GLL(zl + (size_t)c * 16384 + ao, b + 16384 + f * 16);
    }
    int eo = (t >> 7) * 2048 + (t & 127) * 16;      // oct*2048 + col*16
    GLL(eh + (size_t)c * 8192 + eo, b + 32768 + t * 16);
    GLL(el + (size_t)c * 8192 + eo, b + 40960 + t * 16);
}

DEVI void zfill2(char* zb, int t, int r0) {
    floatx4 z4 = {0.f, 0.f, 0.f, 0.f};
    __builtin_nontemporal_store(z4, (floatx4*)(zb + (size_t)r0 * 8192 + t * 16));
    __builtin_nontemporal_store(z4, (floatx4*)(zb + (size_t)(r0 + 1) * 8192 + t * 16));
}

DEVI void compute_chunk(const char* b, int wm, int wn, int g, int rr,
                        floatx4 (&acc_a)[4][4], floatx4 (&acc_b)[4][4]) {
    const char* Ab = b + g * 4096;            // ZH octet base (256 rows x 16B)
    const char* Bb = b + 32768 + g * 2048;    // EH octet base (128 rows x 16B)
    half8 azh[4], azl[4], beh[4], bel[4];
    #pragma unroll
    for (int f = 0; f < 4; ++f) {
        int row = wm * 64 + f * 16 + rr;
        azh[f] = *(const half8*)(Ab + row * 16);
        azl[f] = *(const half8*)(Ab + 16384 + row * 16);
        int col = wn * 64 + f * 16 + rr;
        beh[f] = *(const half8*)(Bb + col * 16);
        bel[f] = *(const half8*)(Bb + 8192 + col * 16);
    }
    __builtin_amdgcn_s_setprio(1);
    #pragma unroll
    for (int fi = 0; fi < 4; ++fi)
        #pragma unroll
        for (int fj = 0; fj < 4; ++fj) {
            acc_a[fi][fj] = __builtin_amdgcn_mfma_f32_16x16x32_f16(azh[fi], beh[fj], acc_a[fi][fj], 0, 0, 0);
            acc_b[fi][fj] = __builtin_amdgcn_mfma_f32_16x16x32_f16(azl[fi], beh[fj], acc_b[fi][fj], 0, 0, 0);
            acc_b[fi][fj] = __builtin_amdgcn_mfma_f32_16x16x32_f16(azh[fi], bel[fj], acc_b[fi][fj], 0, 0, 0);
        }
    __builtin_amdgcn_s_setprio(0);
}

__launch_bounds__(512, 2)
__global__ void vq_gemm_argmin(const _Float16* __restrict__ ZHb, const _Float16* __restrict__ ZLb,
                               const _Float16* __restrict__ EHb, const _Float16* __restrict__ ELb,
                               const float* __restrict__ zz,
                               unsigned long long* __restrict__ keys,
                               char* __restrict__ zfill) {
    __shared__ _Float16 lds[3][24576];                // 3 x 48KB
    __shared__ unsigned long long rowmin[256];

    // XCD-locality: xcd owns bm in [8x, 8x+8) (2MB Z-slice), sweeps bn
    int orig = blockIdx.x;
    int xcd = orig & 7;
    int loc = orig >> 3;                 // 0..511
    int bm = xcd * 8 + (loc & 7);        // 0..63 (256-row Z tiles)
    int bn = loc >> 3;                   // 0..63 (128-row E tiles)
    int m0 = bm * 256, n0v = bn * 128;

    int t = threadIdx.x;
    int lane = t & 63, wid = t >> 6;
    int wm = wid >> 1, wn = wid & 1;     // 4x2 waves of 64x64
    int g = lane >> 4, rr = lane & 15;

    const char* zh = (const char*)ZHb + (size_t)bm * 131072;
    const char* zl = (const char*)ZLb + (size_t)bm * 131072;
    const char* eh = (const char*)EHb + (size_t)bn * 65536;
    const char* el = (const char*)ELb + (size_t)bn * 65536;
    char* zb = zfill + (size_t)orig * ZFILL_PER_BLK;   // this block's 120KB of enc zeros

    floatx4 acc_a[4][4], acc_b[4][4];
    #pragma unroll
    for (int i = 0; i < 4; ++i)
        #pragma unroll
        for (int jj = 0; jj < 4; ++jj) {
            acc_a[i][jj] = (floatx4){0.f, 0.f, 0.f, 0.f};
            acc_b[i][jj] = (floatx4){0.f, 0.f, 0.f, 0.f};
        }

    char* L0 = (char*)lds[0];
    char* L1 = (char*)lds[1];
    char* L2 = (char*)lds[2];

    stage_chunk(zh, zl, eh, el, L0, t, 0);   // 6 outstanding
    stage_chunk(zh, zl, eh, el, L1, t, 1);   // 12
    VM6; BAR;                                // c0 landed; c1 in flight
    stage_chunk(zh, zl, eh, el, L2, t, 2); zfill2(zb, t, 0);  compute_chunk(L0, wm, wn, g, rr, acc_a, acc_b); VM8; BAR;
    stage_chunk(zh, zl, eh, el, L0, t, 3); zfill2(zb, t, 2);  compute_chunk(L1, wm, wn, g, rr, acc_a, acc_b); VM8; BAR;
    stage_chunk(zh, zl, eh, el, L1, t, 4); zfill2(zb, t, 4);  compute_chunk(L2, wm, wn, g, rr, acc_a, acc_b); VM8; BAR;
    stage_chunk(zh, zl, eh, el, L2, t, 5); zfill2(zb, t, 6);  compute_chunk(L0, wm, wn, g, rr, acc_a, acc_b); VM8; BAR;
    stage_chunk(zh, zl, eh, el, L0, t, 6); zfill2(zb, t, 8);  compute_chunk(L1, wm, wn, g, rr, acc_a, acc_b); VM8; BAR;
    stage_chunk(zh, zl, eh, el, L1, t, 7); zfill2(zb, t, 10); compute_chunk(L2, wm, wn, g, rr, acc_a, acc_b); VM8; BAR;
    zfill2(zb, t, 12);                                        compute_chunk(L0, wm, wn, g, rr, acc_a, acc_b); VM2; BAR;
    {
        floatx4 z4 = {0.f, 0.f, 0.f, 0.f};
        __builtin_nontemporal_store(z4, (floatx4*)(zb + 14ull * 8192 + t * 16));
    }
    compute_chunk(L1, wm, wn, g, rr, acc_a, acc_b);

    if (t < 256) rowmin[t] = ~0ull;
    __syncthreads();

    constexpr float S_A = 1.0f / 65536.0f;       // 2^-16
    constexpr float S_B = 1.0f / 134217728.0f;   // 2^-27
    #pragma unroll
    for (int fi = 0; fi < 4; ++fi) {
        #pragma unroll
        for (int r = 0; r < 4; ++r) {
            int rowl = wm * 64 + fi * 16 + g * 4 + r;
            float zzv = zz[m0 + rowl];
            unsigned long long best = ~0ull;
            #pragma unroll
            for (int fj = 0; fj < 4; ++fj) {
                float dot = acc_a[fi][fj][r] * S_A + acc_b[fi][fj][r] * S_B;
                float d = zzv - 2.0f * dot;              // replicates ref fl(zz - fl(2*dot))
                unsigned int db = __float_as_uint(d);    // d > 0 -> bit order == float order
                unsigned int jg = (unsigned)(n0v + wn * 64 + fj * 16 + rr);
                unsigned long long key = ((unsigned long long)db << 32) | jg;
                if (key < best) best = key;
            }
            // cross-lane min over the 16 rr-lanes (same rowl) -> conflict-free atomic
            #pragma unroll
            for (int s = 1; s < 16; s <<= 1) {
                unsigned long long o = __shfl_xor(best, s, 64);
                if (o < best) best = o;
            }
            if (rr == 0) atomicMin(&rowmin[rowl], best);
        }
    }
    __syncthreads();
    if (t < 256) atomicMin(&keys[m0 + t], rowmin[t]);
}

// ---------------- z_q + loss partials + idx output + histogram (fused) ----------------
__global__ void vq_zq_loss(const float* __restrict__ z, const float* __restrict__ cb,
                           const unsigned long long* __restrict__ keys,
                           float* __restrict__ out0, float* __restrict__ parts,
                           float* __restrict__ out_idx, int* __restrict__ hist) {
    size_t i0 = ((size_t)blockIdx.x * 256 + threadIdx.x) * 8;
    int c   = (int)((i0 >> 13) & 255);
    int b   = (int)(i0 >> 21);
    int dhw = (int)(i0 & 8191);
    int nb  = b * DHW_ + dhw;
    int jj[8];
    #pragma unroll
    for (int e = 0; e < 8; ++e)
        jj[e] = (int)(unsigned)(keys[nb + e] & 0xFFFFFFFFull);
    float ls = 0.f;
    #pragma unroll
    for (int e = 0; e < 8; ++e) {
        float zq = cb[(size_t)jj[e] * K_ + c];
        float zt = z[i0 + e];
        float diff = zq - zt;        // fl, matches ref
        out0[i0 + e] = zt + diff;    // fl(z_t + fl(z_q - z_t))
        ls += diff * diff;
    }
    if (c == 0) {
        #pragma unroll
        for (int e = 0; e < 8; ++e) {
            out_idx[nb + e] = (float)jj[e];
            atomicAdd(&hist[jj[e]], 1);
        }
    }
    __shared__ float red[256];
    red[threadIdx.x] = ls;
    __syncthreads();
    for (int s = 128; s > 0; s >>= 1) {
        if (threadIdx.x < (unsigned)s) red[threadIdx.x] += red[threadIdx.x + s];
        __syncthreads();
    }
    if (threadIdx.x == 0) parts[blockIdx.x] = red[0];
}

// ---------------- loss + perplexity ----------------
__global__ void vq_finalize_scalars(const float* __restrict__ parts,
                                    const int* __restrict__ hist,
                                    float* __restrict__ out) {
    __shared__ double dred[256];
    int t = threadIdx.x;
    double ent = 0.0;
    for (int i = t; i < NE_; i += 256) {
        float em = (float)hist[i] * (1.0f / 16384.0f);   // exact (pow2)
        float term = em * logf(em + 1e-10f);
        ent += (double)term;
    }
    dred[t] = ent;
    __syncthreads();
    for (int s = 128; s > 0; s >>= 1) {
        if (t < s) dred[t] += dred[t + s];
        __syncthreads();
    }
    double entr = 0.0;
    if (t == 0) entr = dred[0];
    __syncthreads();
    double ls = 0.0;
    for (int i = t; i < NLOSS_BLOCKS; i += 256) ls += (double)parts[i];
    dred[t] = ls;
    __syncthreads();
    for (int s = 128; s > 0; s >>= 1) {
        if (t < s) dred[t] += dred[t + s];
        __syncthreads();
    }
    if (t == 0) {
        double m = dred[0] / 4194304.0;
        float m1 = (float)m;
        out[LOSS_OFF] = m1 + 0.25f * m1;
        out[PERP_OFF] = (float)exp(-entr);
    }
}

// ---------------- zero the scratch tail + head/tail slivers of enc ----------------
__global__ void vq_zero_tail(char* __restrict__ encb) {
    size_t i = (size_t)blockIdx.x * 256 + threadIdx.x;
    floatx4 z4 = {0.f, 0.f, 0.f, 0.f};
    char* base = encb + TAIL_START;
    for (size_t k = i; k < TAIL_F4; k += 131072)
        *(floatx4*)(base + k * 16) = z4;
    if (i == 0) {
        float2 z2 = {0.f, 0.f};
        *(float2*)encb = z2;                      // enc[0..1]
        *(float2*)(encb + 536870904ull) = z2;     // enc[last two]
    }
}

// ---------------- place the ones ----------------
__global__ void vq_write_ones(const float* __restrict__ idxf, float* __restrict__ enc) {
    int n = blockIdx.x * 256 + threadIdx.x;
    enc[(size_t)n * NE_ + (int)idxf[n]] = 1.0f;
}

extern "C" void kernel_launch(void* const* d_in, const int* in_sizes, int n_in,
                              void* d_out, int out_size, void* d_ws, size_t ws_size,
                              hipStream_t stream) {
    const float* z  = (const float*)d_in[0];
    const float* cb = (const float*)d_in[1];
    float* out = (float*)d_out;

    // 256B-aligned scratch base inside the enc-region tail
    char* scr = (char*)(((uintptr_t)(out + ENC_OFF) + 255) & ~(uintptr_t)255);
    _Float16* ZHb = (_Float16*)(scr + SCR_ZH);
    _Float16* ZLb = (_Float16*)(scr + SCR_ZL);
    _Float16* EHb = (_Float16*)(scr + SCR_EH);
    _Float16* ELb = (_Float16*)(scr + SCR_EL);
    float* zz = (float*)(scr + SCR_ZZ);
    unsigned long long* keys = (unsigned long long*)(scr + SCR_KEY);
    float* parts = (float*)(scr + SCR_PART);
    int* hist = (int*)(scr + SCR_HIST);
    float* out_idx = out + IDX_OFF;
    float* enc = out + ENC_OFF;
    char* encb = (char*)enc;

    vq_split<<<640, 256, 0, stream>>>(z, cb, ZHb, ZLb, EHb, ELb, zz, keys, hist);
    vq_gemm_argmin<<<4096, 512, 0, stream>>>(ZHb, ZLb, EHb, ELb, zz, keys, encb + 8);
    vq_zq_loss<<<NLOSS_BLOCKS, 256, 0, stream>>>(z, cb, keys, out, parts, out_idx, hist);
    vq_finalize_scalars<<<1, 256, 0, stream>>>(parts, hist, out);
    vq_zero_tail<<<512, 256, 0, stream>>>(encb);
    vq_write_ones<<<64, 256, 0, stream>>>(out_idx, enc);
}